// Round 11
// baseline (227.314 us; speedup 1.0000x reference)
//
#include <hip/hip_runtime.h>

// ---------------------------------------------------------------------------
// LoRA_Attention: fold LoRA into weights; bf16 MFMA GEMMs; split-K flash
// attention (S^T core; P transposed to A-layout via quad-shuffles — no Ps
// LDS buffer -> 34.3 KB LDS, 4 blocks/CU, single dispatch round); merge
// fused into proj A-staging (inline normalize). exp2 softmax, no-max
// (scores bounded). XCD-swizzled attn grid. 5 kernels.
// ---------------------------------------------------------------------------

#define DIM   768
#define HEADS 12
#define HD    64
#define NTOK  2304
#define RANK  8
#define GRD   48
#define CHUNKS 4
#define LOG2E 1.44269504088896f
#define OSTR  (HEADS * NTOK * HD)

typedef __attribute__((ext_vector_type(8))) short bf16x8;
typedef __attribute__((ext_vector_type(4))) float f32x4;
typedef unsigned short ushort_t;

__device__ __forceinline__ unsigned short f2bf(float x) {
    union { float f; unsigned u; } v; v.f = x;
    unsigned r = v.u + 0x7fffu + ((v.u >> 16) & 1u);
    return (unsigned short)(r >> 16);
}
__device__ __forceinline__ float bf2f(unsigned short h) {
    return __uint_as_float(((unsigned)h) << 16);
}
__device__ __forceinline__ void gload_lds16(const ushort_t* g, ushort_t* l) {
    __builtin_amdgcn_global_load_lds(
        (const __attribute__((address_space(1))) unsigned int*)g,
        (__attribute__((address_space(3))) unsigned int*)l, 16, 0, 0);
}
__device__ __forceinline__ bf16x8 mk_bf16x8(unsigned a, unsigned b,
                                            unsigned c, unsigned d) {
    union { unsigned u[4]; bf16x8 v; } t;
    t.u[0] = a; t.u[1] = b; t.u[2] = c; t.u[3] = d;
    return t.v;
}

// ---------------------------------------------------------------------------
// k_prep: fold LoRA into transposed weights (2304 blocks) + convert x / rel
// tables to bf16 (blocks < 1740).
// ---------------------------------------------------------------------------
__global__ __launch_bounds__(256) void k_prep(
    const float* __restrict__ x, ushort_t* __restrict__ xb,
    const float* __restrict__ rph, const float* __restrict__ rpw,
    ushort_t* __restrict__ rphb, ushort_t* __restrict__ rpwb,
    const float* __restrict__ Wq, const float* __restrict__ Wk,
    const float* __restrict__ Wv, const float* __restrict__ Wp,
    const float* __restrict__ Aq, const float* __restrict__ Bq,
    const float* __restrict__ Ak, const float* __restrict__ Bk,
    const float* __restrict__ Av, const float* __restrict__ Bv,
    ushort_t* __restrict__ WT) {
    int bid = blockIdx.x, tid = threadIdx.x;

    if (bid < 1740) {
        if (bid < 1728) {
            int idx = (bid * 256 + tid) * 4;
            float4 v = *(const float4*)(x + idx);
            ushort4 o = make_ushort4(f2bf(v.x), f2bf(v.y), f2bf(v.z), f2bf(v.w));
            *(ushort4*)(xb + idx) = o;
        } else {
            int e = ((bid - 1728) * 256 + tid) * 4;
            const int TSZ = (2 * GRD - 1) * HD;   // 6080
            if (e < TSZ) {
                float4 v = *(const float4*)(rph + e);
                ushort4 o = make_ushort4(f2bf(v.x), f2bf(v.y), f2bf(v.z), f2bf(v.w));
                *(ushort4*)(rphb + e) = o;
            } else if (e < 2 * TSZ) {
                float4 v = *(const float4*)(rpw + e - TSZ);
                ushort4 o = make_ushort4(f2bf(v.x), f2bf(v.y), f2bf(v.z), f2bf(v.w));
                *(ushort4*)(rpwb + e - TSZ) = o;
            }
        }
    }

    int kb = (bid % 24) * 32;
    int nb = (bid / 24) * 32;
    int sel = nb / DIM, nmod = nb % DIM;
    const float* W = (sel == 0) ? Wq : (sel == 1) ? Wk : (sel == 2) ? Wv : Wp;
    const float* A = (sel == 0) ? Aq : (sel == 1) ? Ak : Av;
    const float* B = (sel == 0) ? Bq : (sel == 1) ? Bk : Bv;
    __shared__ float T[32][33];
    for (int i = tid; i < 1024; i += 256) {
        int kl = i >> 5, nl = i & 31;
        float v = W[(kb + kl) * DIM + nmod + nl];
        if (sel < 3) {
            #pragma unroll
            for (int r = 0; r < RANK; r++)
                v += A[(kb + kl) * RANK + r] * B[r * DIM + nmod + nl];
        }
        T[kl][nl] = v;
    }
    __syncthreads();
    for (int i = tid; i < 1024; i += 256) {
        int nl = i >> 5, kl = i & 31;
        WT[(size_t)(nb + nl) * DIM + kb + kl] = f2bf(T[kl][nl]);
    }
}

// ---------------------------------------------------------------------------
// QKV GEMM: 128(M)x64(N) tiles -> 648 blocks, BK=32, global_load_lds DMA.
// ---------------------------------------------------------------------------
__global__ __launch_bounds__(256) void k_gemm_qkv(
    const ushort_t* __restrict__ xb, const ushort_t* __restrict__ WT,
    const float* __restrict__ bq, const float* __restrict__ bk,
    const float* __restrict__ bv,
    ushort_t* __restrict__ Qb, ushort_t* __restrict__ Kb,
    ushort_t* __restrict__ Vtb) {
    __shared__ __align__(16) ushort_t As[128 * 32];
    __shared__ __align__(16) ushort_t Bs[64 * 32];
    int tid = threadIdx.x;
    int wave = tid >> 6, lane = tid & 63, quad = lane >> 4, l16 = lane & 15;
    int wx = wave & 1, wy = wave >> 1;
    int nb = blockIdx.x * 64, mb = blockIdx.y * 128;

    f32x4 zero = {0.f, 0.f, 0.f, 0.f};
    f32x4 acc[4][2];
    #pragma unroll
    for (int i = 0; i < 4; i++)
        #pragma unroll
        for (int j = 0; j < 2; j++) acc[i][j] = zero;

    int rl = lane >> 2;
    int cl = (lane & 3) * 8;
    const ushort_t* gA = xb + (size_t)(mb + wave * 32 + rl) * DIM + cl;
    const ushort_t* gB = WT + (size_t)(nb + wave * 16 + rl) * DIM + cl;
    ushort_t* lA = &As[(wave * 32) * 32];
    ushort_t* lB = &Bs[(wave * 16) * 32];

    for (int k0 = 0; k0 < DIM; k0 += 32) {
        __syncthreads();
        gload_lds16(gA + k0,            lA);
        gload_lds16(gA + k0 + 16 * DIM, lA + 16 * 32);
        gload_lds16(gB + k0,            lB);
        __syncthreads();
        bf16x8 af[4], bf[2];
        #pragma unroll
        for (int i = 0; i < 4; i++)
            af[i] = *(const bf16x8*)&As[(wy * 64 + i * 16 + l16) * 32 + quad * 8];
        #pragma unroll
        for (int j = 0; j < 2; j++)
            bf[j] = *(const bf16x8*)&Bs[(wx * 32 + j * 16 + l16) * 32 + quad * 8];
        #pragma unroll
        for (int i = 0; i < 4; i++)
            #pragma unroll
            for (int j = 0; j < 2; j++)
                acc[i][j] = __builtin_amdgcn_mfma_f32_16x16x32_bf16(af[i], bf[j], acc[i][j], 0, 0, 0);
    }

    #pragma unroll
    for (int j = 0; j < 2; j++) {
        int col = nb + wx * 32 + j * 16 + l16;
        int sel = col / DIM, rem = col % DIM;
        int hh = rem >> 6, cc = rem & 63;
        const float* bias = (sel == 0) ? bq : (sel == 1) ? bk : bv;
        float bval = bias[rem];
        #pragma unroll
        for (int i = 0; i < 4; i++) {
            #pragma unroll
            for (int r = 0; r < 4; r++) {
                int row = mb + wy * 64 + i * 16 + quad * 4 + r;
                unsigned short o = f2bf(acc[i][j][r] + bval);
                if (sel == 0)      Qb[(size_t)(hh * NTOK + row) * HD + cc] = o;
                else if (sel == 1) Kb[(size_t)(hh * NTOK + row) * HD + cc] = o;
                else               Vtb[(size_t)(hh * HD + cc) * NTOK + row] = o;
            }
        }
    }
}

// ---------------------------------------------------------------------------
// Rel-pos bias via MFMA (outputs pre-scaled by log2 e).
// ---------------------------------------------------------------------------
__global__ __launch_bounds__(256) void k_relmm(
    const ushort_t* __restrict__ Qb, const ushort_t* __restrict__ rphb,
    const ushort_t* __restrict__ rpwb, float* __restrict__ relH,
    float* __restrict__ relW) {
    int id = blockIdx.x * 4 + (threadIdx.x >> 6);
    int lane = threadIdx.x & 63, quad = lane >> 4, l16 = lane & 15;
    bool isW = id >= 576;
    int t = isW ? id - 576 : id;
    int h = t / GRD, g = t % GRD;
    const ushort_t* tab = isW ? rpwb : rphb;
    float* outp = isW ? relW : relH;

    f32x4 zero = {0.f, 0.f, 0.f, 0.f};
    f32x4 acc[3][3];
    #pragma unroll
    for (int i = 0; i < 3; i++)
        #pragma unroll
        for (int j = 0; j < 3; j++) acc[i][j] = zero;

    bf16x8 bfr[3][2];
    #pragma unroll
    for (int ct = 0; ct < 3; ct++) {
        int trow = g + 47 - (ct * 16 + l16);
        bfr[ct][0] = *(const bf16x8*)&tab[(size_t)trow * HD + quad * 8];
        bfr[ct][1] = *(const bf16x8*)&tab[(size_t)trow * HD + 32 + quad * 8];
    }
    #pragma unroll
    for (int ms = 0; ms < 3; ms++) {
        int m = ms * 16 + l16;
        int n = isW ? m * GRD + g : g * GRD + m;
        bf16x8 a0 = *(const bf16x8*)&Qb[(size_t)(h * NTOK + n) * HD + quad * 8];
        bf16x8 a1 = *(const bf16x8*)&Qb[(size_t)(h * NTOK + n) * HD + 32 + quad * 8];
        #pragma unroll
        for (int ct = 0; ct < 3; ct++) {
            acc[ms][ct] = __builtin_amdgcn_mfma_f32_16x16x32_bf16(a0, bfr[ct][0], acc[ms][ct], 0, 0, 0);
            acc[ms][ct] = __builtin_amdgcn_mfma_f32_16x16x32_bf16(a1, bfr[ct][1], acc[ms][ct], 0, 0, 0);
        }
    }
    #pragma unroll
    for (int ms = 0; ms < 3; ms++) {
        #pragma unroll
        for (int ct = 0; ct < 3; ct++) {
            #pragma unroll
            for (int r = 0; r < 4; r++) {
                int m = ms * 16 + quad * 4 + r;
                int n = isW ? m * GRD + g : g * GRD + m;
                int col = ct * 16 + l16;
                outp[(size_t)(h * NTOK + n) * GRD + col] = acc[ms][ct][r] * LOG2E;
            }
        }
    }
}

// ---------------------------------------------------------------------------
// Flash attention, split-K. Block = (128 q-rows, head, chunk of 576 keys).
// Grid x = h*4+chunk (XCD-local K/V sharing). Coalesced uint4 reg-prefetch
// -> stride-68 LDS; S^T compute. P transposed to PV A-layout via quad
// shuffles (ds_bpermute) — no Ps buffer: LDS 34.3 KB -> 4 blocks/CU, 864
// blocks co-resident in one round.
// ---------------------------------------------------------------------------
__global__ __launch_bounds__(256) void k_attn(
    const ushort_t* __restrict__ Qb, const ushort_t* __restrict__ Kb,
    const ushort_t* __restrict__ Vtb, const float* __restrict__ relH,
    const float* __restrict__ relW, float* __restrict__ Opart,
    float* __restrict__ Lpart) {
    int h = blockIdx.x >> 2, chunk = blockIdx.x & 3, qt = blockIdx.y;
    int tid = threadIdx.x;
    int wave = tid >> 6, lane = tid & 63, quad = lane >> 4, l16 = lane & 15;
    int qbase = qt * 128;
    int kbase = chunk * 576;

    __shared__ __align__(16) ushort_t Ks[64 * 68];      //  8704 B
    __shared__ __align__(16) ushort_t Vs[64 * 68];      //  8704 B
    __shared__ __align__(16) ushort_t rws[128 * 52];    // 13312 B
    __shared__ __align__(16) ushort_t rhs[128 * 14];    //  3584 B  (34.3 KB)

    for (int i = tid; i < 128 * 48; i += 256) {
        int r = i / 48, c = i % 48;
        rws[r * 52 + c] = f2bf(relW[(size_t)(h * NTOK + qbase + r) * GRD + c]);
    }
    for (int i = tid; i < 128 * 12; i += 256) {
        int r = i / 12, c = i % 12;
        rhs[r * 14 + c] = f2bf(relH[(size_t)(h * NTOK + qbase + r) * GRD + chunk * 12 + c]);
    }

    bf16x8 qf[2][2];
    #pragma unroll
    for (int s = 0; s < 2; s++) {
        int qrow = qbase + wave * 32 + s * 16 + l16;
        qf[s][0] = *(const bf16x8*)&Qb[(size_t)(h * NTOK + qrow) * HD + quad * 8];
        qf[s][1] = *(const bf16x8*)&Qb[(size_t)(h * NTOK + qrow) * HD + 32 + quad * 8];
    }

    int r0 = tid >> 3, c0 = (tid & 7) * 8;
    const ushort_t* kg0 = Kb + (size_t)(h * NTOK + r0) * HD + c0;
    const ushort_t* kg1 = Kb + (size_t)(h * NTOK + r0 + 32) * HD + c0;
    const ushort_t* vg0 = Vtb + (size_t)(h * HD + r0) * NTOK + c0;
    const ushort_t* vg1 = Vtb + (size_t)(h * HD + r0 + 32) * NTOK + c0;
    int sk0 = r0 * 68 + c0, sk1 = sk0 + 32 * 68;

    float lacc[2] = {0.f, 0.f};
    f32x4 zero = {0.f, 0.f, 0.f, 0.f};
    f32x4 oacc[2][4];
    #pragma unroll
    for (int s = 0; s < 2; s++)
        #pragma unroll
        for (int cs = 0; cs < 4; cs++) oacc[s][cs] = zero;

    const float scale2 = 0.125f * LOG2E;
    int src0 = l16 + ((quad & 1) << 5);
    int src1 = src0 + 16;

    uint4 rk0 = *(const uint4*)(kg0 + (size_t)kbase * HD);
    uint4 rk1 = *(const uint4*)(kg1 + (size_t)kbase * HD);
    uint4 rv0 = *(const uint4*)(vg0 + kbase);
    uint4 rv1 = *(const uint4*)(vg1 + kbase);

    for (int kt = 0; kt < 9; kt++) {
        int kb = kbase + kt * 64;
        __syncthreads();
        *(uint4*)&Ks[sk0] = rk0;  *(uint4*)&Ks[sk1] = rk1;
        *(uint4*)&Vs[sk0] = rv0;  *(uint4*)&Vs[sk1] = rv1;
        __syncthreads();
        if (kt < 8) {
            int kbn = kb + 64;
            rk0 = *(const uint4*)(kg0 + (size_t)kbn * HD);
            rk1 = *(const uint4*)(kg1 + (size_t)kbn * HD);
            rv0 = *(const uint4*)(vg0 + kbn);
            rv1 = *(const uint4*)(vg1 + kbn);
        }

        #pragma unroll
        for (int half = 0; half < 2; half++) {
            // QK^T (S^T) + softmax; packed P stays in registers
            uint2 w[2][2];   // [strip][ks]
            #pragma unroll
            for (int ks = 0; ks < 2; ks++) {
                int kcol = half * 32 + ks * 16;
                bf16x8 kf0 = *(const bf16x8*)&Ks[(kcol + l16) * 68 + quad * 8];
                bf16x8 kf1 = *(const bf16x8*)&Ks[(kcol + l16) * 68 + 32 + quad * 8];
                f32x4 st[2];
                #pragma unroll
                for (int s = 0; s < 2; s++) {
                    f32x4 z = zero;
                    z = __builtin_amdgcn_mfma_f32_16x16x32_bf16(kf0, qf[s][0], z, 0, 0, 0);
                    z = __builtin_amdgcn_mfma_f32_16x16x32_bf16(kf1, qf[s][1], z, 0, 0, 0);
                    st[s] = z;
                }
                int kb4 = kb + kcol + quad * 4;
                int kh = kb4 / 48;
                int khl = kh - chunk * 12;
                int kw0 = kb4 - kh * 48;
                #pragma unroll
                for (int s = 0; s < 2; s++) {
                    int row = wave * 32 + s * 16 + l16;
                    float rh = bf2f(rhs[row * 14 + khl]);
                    uint2 u = *(const uint2*)&rws[row * 52 + kw0];
                    float p0 = __builtin_amdgcn_exp2f(st[s][0] * scale2 + rh + __uint_as_float(u.x << 16));
                    float p1 = __builtin_amdgcn_exp2f(st[s][1] * scale2 + rh + __uint_as_float(u.x & 0xffff0000u));
                    float p2 = __builtin_amdgcn_exp2f(st[s][2] * scale2 + rh + __uint_as_float(u.y << 16));
                    float p3 = __builtin_amdgcn_exp2f(st[s][3] * scale2 + rh + __uint_as_float(u.y & 0xffff0000u));
                    lacc[s] += (p0 + p1) + (p2 + p3);
                    w[s][ks].x = __builtin_amdgcn_perm(__float_as_uint(p1), __float_as_uint(p0), 0x07060302u);
                    w[s][ks].y = __builtin_amdgcn_perm(__float_as_uint(p3), __float_as_uint(p2), 0x07060302u);
                }
            }

            // transpose S^T -> PV A-layout via quad shuffles
            bf16x8 pa[2];
            #pragma unroll
            for (int s = 0; s < 2; s++) {
                unsigned a0 = (unsigned)__shfl((int)w[s][0].x, src0);
                unsigned a1 = (unsigned)__shfl((int)w[s][0].y, src0);
                unsigned a2 = (unsigned)__shfl((int)w[s][0].x, src1);
                unsigned a3 = (unsigned)__shfl((int)w[s][0].y, src1);
                unsigned b0 = (unsigned)__shfl((int)w[s][1].x, src0);
                unsigned b1 = (unsigned)__shfl((int)w[s][1].y, src0);
                unsigned b2 = (unsigned)__shfl((int)w[s][1].x, src1);
                unsigned b3 = (unsigned)__shfl((int)w[s][1].y, src1);
                bool lo = (quad < 2);
                pa[s] = mk_bf16x8(lo ? a0 : b0, lo ? a1 : b1,
                                  lo ? a2 : b2, lo ? a3 : b3);
            }

            // PV for this 32-key half
            bf16x8 vf[4];
            #pragma unroll
            for (int cs = 0; cs < 4; cs++)
                vf[cs] = *(const bf16x8*)&Vs[(cs * 16 + l16) * 68 + half * 32 + quad * 8];
            #pragma unroll
            for (int s = 0; s < 2; s++)
                #pragma unroll
                for (int cs = 0; cs < 4; cs++)
                    oacc[s][cs] = __builtin_amdgcn_mfma_f32_16x16x32_bf16(pa[s], vf[cs], oacc[s][cs], 0, 0, 0);
        }
    }

    #pragma unroll
    for (int s = 0; s < 2; s++) {
        float l = lacc[s];
        l += __shfl_xor(l, 16);
        l += __shfl_xor(l, 32);
        lacc[s] = l;
    }

    size_t obase = (size_t)(chunk * HEADS + h) * NTOK;
    #pragma unroll
    for (int s = 0; s < 2; s++) {
        #pragma unroll
        for (int cs = 0; cs < 4; cs++) {
            #pragma unroll
            for (int r = 0; r < 4; r++) {
                int row = qbase + wave * 32 + s * 16 + quad * 4 + r;
                Opart[(obase + row) * HD + cs * 16 + l16] = oacc[s][cs][r];
            }
        }
        if (quad == 0)
            Lpart[obase + qbase + wave * 32 + s * 16 + l16] = lacc[s];
    }
}

// ---------------------------------------------------------------------------
// Output projection with fused split-K merge: A-staging reads 4 Opart chunks,
// normalizes by 1/l (precomputed in LDS), packs bf16 into As. B via DMA.
// 128(M)x64(N) tiles, grid x = mb (Opart-sharing blocks XCD-close).
// ---------------------------------------------------------------------------
__global__ __launch_bounds__(256) void k_gemm_proj(
    const float* __restrict__ Opart, const float* __restrict__ Lpart,
    const ushort_t* __restrict__ WTp, const float* __restrict__ bp,
    float* __restrict__ out) {
    __shared__ __align__(16) ushort_t As[128 * 32];   // 8 KB
    __shared__ __align__(16) ushort_t Bs[64 * 32];    // 4 KB
    __shared__ float Ls[12 * 128];                    // 6 KB inv-l [head][row]
    int tid = threadIdx.x;
    int wave = tid >> 6, lane = tid & 63, quad = lane >> 4, l16 = lane & 15;
    int wx = wave & 1, wy = wave >> 1;
    int mb = blockIdx.x * 128, nb = blockIdx.y * 64;

    // inv-l for this mb stripe
    for (int e = tid; e < 12 * 128; e += 256) {
        int hh = e >> 7, r = e & 127;
        float l = 0.f;
        #pragma unroll
        for (int ch = 0; ch < CHUNKS; ch++)
            l += Lpart[(size_t)(ch * HEADS + hh) * NTOK + mb + r];
        Ls[e] = 1.0f / l;
    }

    f32x4 zero = {0.f, 0.f, 0.f, 0.f};
    f32x4 acc[4][2];
    #pragma unroll
    for (int i = 0; i < 4; i++)
        #pragma unroll
        for (int j = 0; j < 2; j++) acc[i][j] = zero;

    int rl = lane >> 2, cl = (lane & 3) * 8;
    const ushort_t* gB = WTp + (size_t)(nb + wave * 16 + rl) * DIM + cl;
    ushort_t* lB = &Bs[(wave * 16) * 32];

    int r2 = tid >> 1, chalf = (tid & 1) * 16;

    for (int k0 = 0; k0 < DIM; k0 += 32) {
        int h0 = k0 >> 6;                 // head for this col-slice (32 | 64)
        int cb = (k0 & 63) + chalf;       // col base within head
        __syncthreads();
        gload_lds16(gB + k0, lB);
        // A: merge 4 chunks + normalize + pack
        float linv = Ls[h0 * 128 + r2];
        size_t abase = ((size_t)h0 * NTOK + mb + r2) * HD + cb;
        float4 sA[4];
        #pragma unroll
        for (int i = 0; i < 4; i++) sA[i] = make_float4(0.f, 0.f, 0.f, 0.f);
        #pragma unroll
        for (int ch = 0; ch < CHUNKS; ch++) {
            const float* p = Opart + (size_t)ch * OSTR + abase;
            #pragma unroll
            for (int i = 0; i < 4; i++) {
                float4 v = *(const float4*)(p + i * 4);
                sA[i].x += v.x; sA[i].y += v.y; sA[i].z += v.z; sA[i].w += v.w;
            }
        }
        #pragma unroll
        for (int i = 0; i < 4; i++) {
            ushort4 o = make_ushort4(f2bf(sA[i].x * linv), f2bf(sA[i].y * linv),
                                     f2bf(sA[i].z * linv), f2bf(sA[i].w * linv));
            *(ushort4*)&As[r2 * 32 + chalf + i * 4] = o;
        }
        __syncthreads();
        bf16x8 af[4], bf[2];
        #pragma unroll
        for (int i = 0; i < 4; i++)
            af[i] = *(const bf16x8*)&As[(wy * 64 + i * 16 + l16) * 32 + quad * 8];
        #pragma unroll
        for (int j = 0; j < 2; j++)
            bf[j] = *(const bf16x8*)&Bs[(wx * 32 + j * 16 + l16) * 32 + quad * 8];
        #pragma unroll
        for (int i = 0; i < 4; i++)
            #pragma unroll
            for (int j = 0; j < 2; j++)
                acc[i][j] = __builtin_amdgcn_mfma_f32_16x16x32_bf16(af[i], bf[j], acc[i][j], 0, 0, 0);
    }

    #pragma unroll
    for (int j = 0; j < 2; j++) {
        int col = nb + wx * 32 + j * 16 + l16;
        float bval = bp[col];
        #pragma unroll
        for (int i = 0; i < 4; i++) {
            #pragma unroll
            for (int r = 0; r < 4; r++) {
                int row = mb + wy * 64 + i * 16 + quad * 4 + r;
                out[(size_t)row * DIM + col] = acc[i][j][r] + bval;
            }
        }
    }
}

// ---------------------------------------------------------------------------
extern "C" void kernel_launch(void* const* d_in, const int* in_sizes, int n_in,
                              void* d_out, int out_size, void* d_ws, size_t ws_size,
                              hipStream_t stream) {
    const float* x   = (const float*)d_in[0];
    const float* Wq  = (const float*)d_in[1];
    const float* bq  = (const float*)d_in[2];
    const float* Wk  = (const float*)d_in[3];
    const float* bk  = (const float*)d_in[4];
    const float* Wv  = (const float*)d_in[5];
    const float* bv  = (const float*)d_in[6];
    const float* Wp  = (const float*)d_in[7];
    const float* bp  = (const float*)d_in[8];
    const float* rph = (const float*)d_in[9];
    const float* rpw = (const float*)d_in[10];
    const float* Aq  = (const float*)d_in[11];
    const float* Bq  = (const float*)d_in[12];
    const float* Ak  = (const float*)d_in[13];
    const float* Bk  = (const float*)d_in[14];
    const float* Av  = (const float*)d_in[15];
    const float* Bv  = (const float*)d_in[16];
    float* out = (float*)d_out;

    char* w = (char*)d_ws;
    size_t off = 0;
    auto carve = [&](size_t bytes) {
        char* p = w + off;
        off += (bytes + 255) & ~(size_t)255;
        return p;
    };
    ushort_t* xb    = (ushort_t*)carve((size_t)NTOK * DIM * 2);
    ushort_t* WT    = (ushort_t*)carve((size_t)4 * DIM * DIM * 2);
    ushort_t* Qb    = (ushort_t*)carve((size_t)HEADS * NTOK * HD * 2);
    ushort_t* Kb    = (ushort_t*)carve((size_t)HEADS * NTOK * HD * 2);
    ushort_t* Vtb   = (ushort_t*)carve((size_t)HEADS * HD * NTOK * 2);
    float*    relH  = (float*)carve((size_t)HEADS * NTOK * GRD * 4);
    float*    relW  = (float*)carve((size_t)HEADS * NTOK * GRD * 4);
    float*    Opart = (float*)carve((size_t)CHUNKS * HEADS * NTOK * HD * 4);
    float*    Lpart = (float*)carve((size_t)CHUNKS * HEADS * NTOK * 4);
    ushort_t* rphb  = (ushort_t*)carve((size_t)(2 * GRD - 1) * HD * 2);
    ushort_t* rpwb  = (ushort_t*)carve((size_t)(2 * GRD - 1) * HD * 2);

    k_prep<<<dim3(2304), dim3(256), 0, stream>>>(
        x, xb, rph, rpw, rphb, rpwb,
        Wq, Wk, Wv, Wp, Aq, Bq, Ak, Bk, Av, Bv, WT);
    k_gemm_qkv<<<dim3(36, 18), dim3(256), 0, stream>>>(
        xb, WT, bq, bk, bv, Qb, Kb, Vtb);
    k_relmm<<<dim3(288), dim3(256), 0, stream>>>(
        Qb, rphb, rpwb, relH, relW);
    k_attn<<<dim3(HEADS * CHUNKS, NTOK / 128), dim3(256), 0, stream>>>(
        Qb, Kb, Vtb, relH, relW, Opart, Lpart);
    k_gemm_proj<<<dim3(18, 12), dim3(256), 0, stream>>>(
        Opart, Lpart, WT + (size_t)3 * DIM * DIM, bp, out);
}